// Round 7
// baseline (1007.318 us; speedup 1.0000x reference)
//
#include <hip/hip_runtime.h>

typedef short v8s __attribute__((ext_vector_type(8)));
typedef float v4f __attribute__((ext_vector_type(4)));

#define T_TOK 2048
#define DD 2048
#define FF 4096
#define EE 8
#define BMG 256
#define MT1 24
#define MT2 48
#define MAXROWS 6144

// workspace layout (bytes)
#define WS_COUNTS 0
#define WS_FILL   32
#define WS_ROWOFF 64
#define WS_TOPE   128
#define WS_TOPW   (WS_TOPE + T_TOK * 2 * 4)
#define WS_IDS    (WS_TOPW + T_TOK * 2 * 4)   // 32896
#define WS_WTS    (WS_IDS + MAXROWS * 4)      // 57472
#define WS_ZERO   (WS_WTS + MAXROWS * 4)      // 82048 zeroed each launch
#define WS_XB     82176ul                     // bf16 X [2048][2048] = 8 MB
#define WS_GH     (WS_XB + 8388608ul)         // bf16 H [6144][4096] = 50.3 MB

// chunk swizzle for [row][64 bf16] LDS tiles (128B rows, 8x16B chunks):
// slot = chunk ^ SW(row). Verified numerically in R4.
#define SW(r) (((r) ^ ((r) >> 3)) & 7)

#define VMCNT0() asm volatile("s_waitcnt vmcnt(0)" ::: "memory")
#define LGKM0()  asm volatile("s_waitcnt lgkmcnt(0)" ::: "memory")
#define BARR()   __builtin_amdgcn_s_barrier()
#define CFENCE() asm volatile("" ::: "memory")
#define SCHEDB() __builtin_amdgcn_sched_barrier(0)

static __device__ __forceinline__ short f2bf(float f) {
  return __builtin_bit_cast(short, static_cast<__bf16>(f));
}

// async global->LDS 16B/lane; dest = wave-uniform base + lane*16 (HW).
static __device__ __forceinline__ void gload_lds16(const void* g, void* l) {
  __builtin_amdgcn_global_load_lds(
      (const __attribute__((address_space(1))) unsigned int*)g,
      (__attribute__((address_space(3))) unsigned int*)l, 16, 0, 0);
}

// ---------------- X -> bf16 ----------------
__global__ __launch_bounds__(256) void xbf_k(const float* __restrict__ x,
                                             unsigned short* __restrict__ xb) {
  const int i = (blockIdx.x * 256 + threadIdx.x) * 8;
  v4f a = *(const v4f*)(x + i);
  v4f b = *(const v4f*)(x + i + 4);
  v8s h;
  h[0] = f2bf(a[0]); h[1] = f2bf(a[1]); h[2] = f2bf(a[2]); h[3] = f2bf(a[3]);
  h[4] = f2bf(b[0]); h[5] = f2bf(b[1]); h[6] = f2bf(b[2]); h[7] = f2bf(b[3]);
  *(v8s*)(xb + i) = h;
}

// ---------------- router: fp32 logits, softmax, top-2 ----------------
__global__ __launch_bounds__(256) void router_k(
    const float* __restrict__ x, const float* __restrict__ gw,
    int* __restrict__ counts, int* __restrict__ tope, float* __restrict__ topw) {
  const int lane = threadIdx.x & 63;
  const int t = blockIdx.x * 4 + (threadIdx.x >> 6);
  if (t >= T_TOK) return;
  float acc[EE] = {0.f, 0.f, 0.f, 0.f, 0.f, 0.f, 0.f, 0.f};
  const float* xr = x + (size_t)t * DD;
  for (int i = 0; i < DD / 64; ++i) {
    int k = i * 64 + lane;
    float xv = xr[k];
    const v4f* g = (const v4f*)(gw + (size_t)k * EE);
    v4f g0 = g[0], g1 = g[1];
    acc[0] += xv * g0[0]; acc[1] += xv * g0[1]; acc[2] += xv * g0[2]; acc[3] += xv * g0[3];
    acc[4] += xv * g1[0]; acc[5] += xv * g1[1]; acc[6] += xv * g1[2]; acc[7] += xv * g1[3];
  }
  #pragma unroll
  for (int e = 0; e < EE; ++e) {
    #pragma unroll
    for (int off = 32; off > 0; off >>= 1) acc[e] += __shfl_xor(acc[e], off);
  }
  if (lane == 0) {
    float m = acc[0];
    #pragma unroll
    for (int e = 1; e < EE; ++e) m = fmaxf(m, acc[e]);
    float p[EE], s = 0.f;
    #pragma unroll
    for (int e = 0; e < EE; ++e) { p[e] = expf(acc[e] - m); s += p[e]; }
    float inv = 1.f / s;
    #pragma unroll
    for (int e = 0; e < EE; ++e) p[e] *= inv;
    int e1 = 0;
    #pragma unroll
    for (int e = 1; e < EE; ++e) if (p[e] > p[e1]) e1 = e;
    int e2 = (e1 == 0) ? 1 : 0;
    #pragma unroll
    for (int e = 0; e < EE; ++e) if (e != e1 && p[e] > p[e2]) e2 = e;
    tope[2 * t] = e1;  tope[2 * t + 1] = e2;
    topw[2 * t] = p[e1]; topw[2 * t + 1] = p[e2];
    atomicAdd(&counts[e1], 1);
    atomicAdd(&counts[e2], 1);
  }
}

// ---------------- per-expert padded row offsets (granularity 256) ----------------
__global__ void offsets_k(const int* __restrict__ counts, int* __restrict__ rowoff) {
  if (threadIdx.x == 0) {
    int off = 0;
    #pragma unroll
    for (int e = 0; e < EE; ++e) {
      rowoff[e] = off;
      off += ((counts[e] + BMG - 1) / BMG) * BMG;
    }
  }
}

// ---------------- scatter ----------------
__global__ __launch_bounds__(256) void scatter_k(
    const int* __restrict__ tope, const float* __restrict__ topw,
    const int* __restrict__ rowoff, int* __restrict__ fill,
    int* __restrict__ ids, float* __restrict__ wts) {
  const int t = blockIdx.x * 256 + threadIdx.x;
  if (t >= T_TOK) return;
  #pragma unroll
  for (int j = 0; j < 2; ++j) {
    int e = tope[2 * t + j];
    int pos = rowoff[e] + atomicAdd(&fill[e], 1);
    ids[pos] = t;
    wts[pos] = topw[2 * t + j];
  }
}

// expert for a global row (padded region granularity 256)
static __device__ __forceinline__ int find_e(
    const int* counts, const int* rowoff, int row) {
  int expert = -1;
  #pragma unroll
  for (int e = 0; e < EE; ++e) {
    int rs = rowoff[e];
    int tl = (counts[e] + BMG - 1) / BMG;
    if (row >= rs && row < rs + tl * BMG) expert = e;
  }
  return expert;
}

// XCD-aware bijective swizzle (both grids have nwg % 8 == 0).
static __device__ __forceinline__ void xcd_map(int* nt, int* mt) {
  int gx = gridDim.x, gy = gridDim.y;
  int nwg = gx * gy;
  int lin = blockIdx.y * gx + blockIdx.x;
  int q = nwg >> 3;
  int s = (lin & 7) * q + (lin >> 3);
  *nt = s / gy;
  *mt = s % gy;
}

// ============ GEMM1: H = silu(Xb@W1) * (Xb@W3) ============
// 256 rows x 128 f x 2 mats. 8 waves (4R x 2C), wave 64x64xboth. BK=64.
// A: gload_lds (source-swizzled). B: reg fp32 -> bf16 swizzled LDS.
// Schedule: C(t); bar; vmcnt0; writeB(t+1); issue(t+2); lgkm0; bar.
__global__ __launch_bounds__(512, 2) void g1_k(
    const unsigned short* __restrict__ xb, const float* __restrict__ w1,
    const float* __restrict__ w3, const int* __restrict__ counts,
    const int* __restrict__ rowoff, const int* __restrict__ ids,
    unsigned short* __restrict__ gh) {
  extern __shared__ char smem[];   // [2][A 32KB | B1 16KB | B3 16KB] = 128KB
  int nt, mt;
  xcd_map(&nt, &mt);
  const int expert = find_e(counts, rowoff, mt * 256);
  if (expert < 0) return;
  const int m0 = mt * 256, n0 = nt * 128;

  const int tid = threadIdx.x, lane = tid & 63, wid = tid >> 6;
  const int lr = lane & 15, lg = lane >> 4;
  const int wr = wid >> 1, wcol = wid & 1;

  // A gload: 4 instr/wave; instr s covers rows wid*32+s*8 .. +7, lane->row (lane>>3), chunk lane&7
  const unsigned short* asrc[4];
  #pragma unroll
  for (int s = 0; s < 4; ++s) {
    int r = wid * 32 + s * 8 + (lane >> 3);
    asrc[s] = xb + (size_t)ids[m0 + r] * DD + (((lane & 7) ^ SW(r)) << 3);
  }
  // B: threads 0-255 -> w1, 256-511 -> w3; each 4f x 8k
  const int bmat = tid >> 8, bidx = tid & 255;
  const int f4 = (bidx & 31) * 4, k8 = (bidx >> 5) * 8;
  const float* bsrc = (bmat ? w3 : w1) + (size_t)expert * DD * FF
                      + (size_t)k8 * FF + n0 + f4;

  v4f rb[8];
  #define G1_AISS(KT, BUF) { _Pragma("unroll") for (int s_ = 0; s_ < 4; ++s_)   \
      gload_lds16(asrc[s_] + (size_t)(KT) * 64,                                 \
                  smem + (BUF) * 65536 + (wid * 32 + s_ * 8) * 128); }
  #define G1_BL(KT) { const float* p_ = bsrc + (size_t)(KT) * 64 * FF;          \
      _Pragma("unroll") for (int j = 0; j < 8; ++j)                             \
        rb[j] = *(const v4f*)(p_ + (size_t)j * FF); }
  #define G1_BW(BUF) { char* bb_ = smem + (BUF) * 65536 + 32768 + bmat * 16384; \
      _Pragma("unroll") for (int c = 0; c < 4; ++c) { v8s h_;                   \
        _Pragma("unroll") for (int j = 0; j < 8; ++j) h_[j] = f2bf(rb[j][c]);   \
        int f_ = f4 + c;                                                        \
        *(v8s*)(bb_ + f_ * 128 + ((((k8) >> 3) ^ SW(f_)) << 4)) = h_; } }

  v4f acc1[4][4], acc3[4][4];
  #pragma unroll
  for (int i = 0; i < 4; ++i)
    #pragma unroll
    for (int j = 0; j < 4; ++j) {
      acc1[i][j] = (v4f){0.f, 0.f, 0.f, 0.f};
      acc3[i][j] = (v4f){0.f, 0.f, 0.f, 0.f};
    }

  G1_AISS(0, 0); G1_BL(0);
  VMCNT0();
  G1_BW(0);
  G1_AISS(1, 1); G1_BL(1);
  SCHEDB(); LGKM0(); BARR(); CFENCE();

  const int NKT = DD / 64;  // 32
  #pragma unroll 2
  for (int kt = 0; kt < NKT; ++kt) {
    const int cur = kt & 1;
    const char* ab = smem + cur * 65536;
    const char* b1b = ab + 32768;
    const char* b3b = ab + 49152;
    #pragma unroll
    for (int ks = 0; ks < 2; ++ks) {
      v8s a[4], b1[4], b3[4];
      #pragma unroll
      for (int n = 0; n < 4; ++n) {
        int f = wcol * 64 + n * 16 + lr;
        int sl = (ks * 4 + lg) ^ SW(f);
        b1[n] = *(const v8s*)(b1b + f * 128 + (sl << 4));
        b3[n] = *(const v8s*)(b3b + f * 128 + (sl << 4));
      }
      #pragma unroll
      for (int m = 0; m < 4; ++m) {
        int r = wr * 64 + m * 16 + lr;
        int sl = (ks * 4 + lg) ^ SW(r);
        a[m] = *(const v8s*)(ab + r * 128 + (sl << 4));
      }
      #pragma unroll
      for (int m = 0; m < 4; ++m)
        #pragma unroll
        for (int n = 0; n < 4; ++n) {
          acc1[m][n] = __builtin_amdgcn_mfma_f32_16x16x32_bf16(a[m], b1[n], acc1[m][n], 0, 0, 0);
          acc3[m][n] = __builtin_amdgcn_mfma_f32_16x16x32_bf16(a[m], b3[n], acc3[m][n], 0, 0, 0);
        }
    }
    CFENCE(); BARR(); CFENCE();
    if (kt + 1 < NKT) {
      VMCNT0();                       // drains A(t+1) gloads + B(t+1) regs only
      G1_BW(cur ^ 1);
      if (kt + 2 < NKT) { G1_AISS(kt + 2, cur); G1_BL(kt + 2); }
      SCHEDB(); LGKM0();
    }
    CFENCE(); BARR(); CFENCE();
  }

  // epilogue: in-wave silu fusion
  #pragma unroll
  for (int m = 0; m < 4; ++m)
    #pragma unroll
    for (int n = 0; n < 4; ++n)
      #pragma unroll
      for (int r_ = 0; r_ < 4; ++r_) {
        int row = wr * 64 + m * 16 + lg * 4 + r_;
        int col = wcol * 64 + n * 16 + lr;
        float g = acc1[m][n][r_];
        float u = acc3[m][n][r_];
        gh[(size_t)(m0 + row) * FF + (n0 + col)] =
            (unsigned short)f2bf((g / (1.f + expf(-g))) * u);
      }
}

// ============ GEMM2: out[tok] += wgt * (H @ W2) ============
// 128 rows x 256 d. 8 waves (2R x 4C), wave 64x64. BK=64, 96KB LDS.
__global__ __launch_bounds__(512, 2) void g2_k(
    const unsigned short* __restrict__ gh, const float* __restrict__ w2,
    const int* __restrict__ counts, const int* __restrict__ rowoff,
    const int* __restrict__ ids, const float* __restrict__ wts,
    float* __restrict__ out) {
  extern __shared__ char smem[];   // [2][A 16KB | B 32KB] = 96KB
  int nt, mt;
  xcd_map(&nt, &mt);
  const int expert = find_e(counts, rowoff, mt * 128);
  if (expert < 0) return;
  const int m0 = mt * 128, n0 = nt * 256;

  const int tid = threadIdx.x, lane = tid & 63, wid = tid >> 6;
  const int lr = lane & 15, lg = lane >> 4;
  const int wr = wid >> 2, wq = wid & 3;

  // A gload: 2 instr/wave (rows wid*16+s*8..+7)
  const unsigned short* asrc[2];
  #pragma unroll
  for (int s = 0; s < 2; ++s) {
    int r = wid * 16 + s * 8 + (lane >> 3);
    asrc[s] = gh + (size_t)(m0 + r) * FF + (((lane & 7) ^ SW(r)) << 3);
  }
  // B: 512 thr cover 256d x 64k: 4d x 8k each
  const int d4 = (tid & 63) * 4, k8 = (tid >> 6) * 8;
  const float* bsrc = w2 + (size_t)expert * FF * DD + (size_t)k8 * DD + n0 + d4;

  v4f rb[8];
  #define G2_AISS(KT, BUF) { _Pragma("unroll") for (int s_ = 0; s_ < 2; ++s_)   \
      gload_lds16(asrc[s_] + (size_t)(KT) * 64,                                 \
                  smem + (BUF) * 49152 + (wid * 16 + s_ * 8) * 128); }
  #define G2_BL(KT) { const float* p_ = bsrc + (size_t)(KT) * 64 * DD;          \
      _Pragma("unroll") for (int j = 0; j < 8; ++j)                             \
        rb[j] = *(const v4f*)(p_ + (size_t)j * DD); }
  #define G2_BW(BUF) { char* bb_ = smem + (BUF) * 49152 + 16384;                \
      _Pragma("unroll") for (int c = 0; c < 4; ++c) { v8s h_;                   \
        _Pragma("unroll") for (int j = 0; j < 8; ++j) h_[j] = f2bf(rb[j][c]);   \
        int f_ = d4 + c;                                                        \
        *(v8s*)(bb_ + f_ * 128 + ((((k8) >> 3) ^ SW(f_)) << 4)) = h_; } }

  v4f acc[4][4];
  #pragma unroll
  for (int i = 0; i < 4; ++i)
    #pragma unroll
    for (int j = 0; j < 4; ++j) acc[i][j] = (v4f){0.f, 0.f, 0.f, 0.f};

  G2_AISS(0, 0); G2_BL(0);
  VMCNT0();
  G2_BW(0);
  G2_AISS(1, 1); G2_BL(1);
  SCHEDB(); LGKM0(); BARR(); CFENCE();

  const int NKT = FF / 64;  // 64
  #pragma unroll 2
  for (int kt = 0; kt < NKT; ++kt) {
    const int cur = kt & 1;
    const char* ab = smem + cur * 49152;
    const char* bb = ab + 16384;
    #pragma unroll
    for (int ks = 0; ks < 2; ++ks) {
      v8s a[4], b[4];
      #pragma unroll
      for (int n = 0; n < 4; ++n) {
        int f = wq * 64 + n * 16 + lr;
        int sl = (ks * 4 + lg) ^ SW(f);
        b[n] = *(const v8s*)(bb + f * 128 + (sl << 4));
      }
      #pragma unroll
      for (int m = 0; m < 4; ++m) {
        int r = wr * 64 + m * 16 + lr;
        int sl = (ks * 4 + lg) ^ SW(r);
        a[m] = *(const v8s*)(ab + r * 128 + (sl << 4));
      }
      #pragma unroll
      for (int m = 0; m < 4; ++m)
        #pragma unroll
        for (int n = 0; n < 4; ++n)
          acc[m][n] = __builtin_amdgcn_mfma_f32_16x16x32_bf16(a[m], b[n], acc[m][n], 0, 0, 0);
    }
    CFENCE(); BARR(); CFENCE();
    if (kt + 1 < NKT) {
      VMCNT0();
      G2_BW(cur ^ 1);
      if (kt + 2 < NKT) { G2_AISS(kt + 2, cur); G2_BL(kt + 2); }
      SCHEDB(); LGKM0();
    }
    CFENCE(); BARR(); CFENCE();
  }

  #pragma unroll
  for (int m = 0; m < 4; ++m)
    #pragma unroll
    for (int r_ = 0; r_ < 4; ++r_) {
      int row = m0 + wr * 64 + m * 16 + lg * 4 + r_;
      float wgt = wts[row];
      if (wgt != 0.f) {
        float* orow = out + (size_t)ids[row] * DD + n0 + wq * 64 + lr;
        #pragma unroll
        for (int n = 0; n < 4; ++n)
          atomicAdd(orow + n * 16, wgt * acc[m][n][r_]);
      }
    }
}

extern "C" void kernel_launch(void* const* d_in, const int* in_sizes, int n_in,
                              void* d_out, int out_size, void* d_ws, size_t ws_size,
                              hipStream_t stream) {
  const float* x  = (const float*)d_in[0];
  const float* gw = (const float*)d_in[1];
  const float* w1 = (const float*)d_in[2];
  const float* w3 = (const float*)d_in[3];
  const float* w2 = (const float*)d_in[4];
  float* out = (float*)d_out;
  char* ws = (char*)d_ws;

  int*   counts = (int*)(ws + WS_COUNTS);
  int*   fill   = (int*)(ws + WS_FILL);
  int*   rowoff = (int*)(ws + WS_ROWOFF);
  int*   tope   = (int*)(ws + WS_TOPE);
  float* topw   = (float*)(ws + WS_TOPW);
  int*   ids    = (int*)(ws + WS_IDS);
  float* wts    = (float*)(ws + WS_WTS);
  unsigned short* xb = (unsigned short*)(ws + WS_XB);
  unsigned short* gh = (unsigned short*)(ws + WS_GH);

  hipMemsetAsync(ws, 0, WS_ZERO, stream);
  hipMemsetAsync(d_out, 0, (size_t)out_size * sizeof(float), stream);

  xbf_k<<<T_TOK * DD / (256 * 8), 256, 0, stream>>>(x, xb);
  router_k<<<T_TOK / 4, 256, 0, stream>>>(x, gw, counts, tope, topw);
  offsets_k<<<1, 64, 0, stream>>>(counts, rowoff);
  scatter_k<<<T_TOK / 256, 256, 0, stream>>>(tope, topw, rowoff, fill, ids, wts);
  g1_k<<<dim3(FF / 128, MT1), 512, 131072, stream>>>(xb, w1, w3, counts, rowoff, ids, gh);
  g2_k<<<dim3(DD / 256, MT2), 512, 98304, stream>>>(gh, w2, counts, rowoff, ids, wts, out);
}

// Round 8
// 544.979 us; speedup vs baseline: 1.8484x; 1.8484x over previous
//
#include <hip/hip_runtime.h>

typedef short v8s __attribute__((ext_vector_type(8)));
typedef float v4f __attribute__((ext_vector_type(4)));
typedef float v16f __attribute__((ext_vector_type(16)));

#define T_TOK 2048
#define DD 2048
#define FF 4096
#define EE 8
#define BM 128
#define BN 128
#define BK 64
#define MT_MAX 40
#define MAXROWS 5120

// workspace layout (bytes)
#define WS_COUNTS 0
#define WS_FILL   32
#define WS_ROWOFF 64
#define WS_TOPE   128
#define WS_TOPW   (WS_TOPE + T_TOK * 2 * 4)   // 16512
#define WS_IDS    (WS_TOPW + T_TOK * 2 * 4)   // 32896
#define WS_WTS    (WS_IDS + MAXROWS * 4)      // 53376
#define WS_ZERO   (WS_WTS + MAXROWS * 4)      // 73856 zeroed each launch
#define WS_XB     73984ul                     // bf16 X [2048][2048] = 8 MB
#define WS_H      (WS_XB + 8388608ul)         // bf16 H [5120][4096] = 41.9 MB

// XOR-swizzled byte offset within a [rows][64 bf16] LDS tile (128B rows).
// Verified in R4: spreads stride-4 staging writes AND frag reads.
#define SWZ(r, kb) ((r) * 128 + ((kb) ^ ((((r) ^ ((r) >> 3)) & 7) << 4)))

static __device__ __forceinline__ short f2bf(float f) {
  return __builtin_bit_cast(short, static_cast<__bf16>(f));
}

// ---------------- X -> bf16 (removes A-cvt from gemm1 hot loop) ----------------
__global__ __launch_bounds__(256) void xbf_k(const float* __restrict__ x,
                                             unsigned short* __restrict__ xb) {
  const int i = (blockIdx.x * 256 + threadIdx.x) * 8;
  v4f a = *(const v4f*)(x + i);
  v4f b = *(const v4f*)(x + i + 4);
  v8s h;
  h[0] = f2bf(a[0]); h[1] = f2bf(a[1]); h[2] = f2bf(a[2]); h[3] = f2bf(a[3]);
  h[4] = f2bf(b[0]); h[5] = f2bf(b[1]); h[6] = f2bf(b[2]); h[7] = f2bf(b[3]);
  *(v8s*)(xb + i) = h;
}

// ---------------- router: fp32 logits, softmax, top-2 ----------------
__global__ __launch_bounds__(256) void router_k(
    const float* __restrict__ x, const float* __restrict__ gw,
    int* __restrict__ counts, int* __restrict__ tope, float* __restrict__ topw) {
  const int lane = threadIdx.x & 63;
  const int t = blockIdx.x * 4 + (threadIdx.x >> 6);
  if (t >= T_TOK) return;
  float acc[EE] = {0.f, 0.f, 0.f, 0.f, 0.f, 0.f, 0.f, 0.f};
  const float* xr = x + (size_t)t * DD;
  for (int i = 0; i < DD / 64; ++i) {
    int k = i * 64 + lane;
    float xv = xr[k];
    const v4f* g = (const v4f*)(gw + (size_t)k * EE);
    v4f g0 = g[0], g1 = g[1];
    acc[0] += xv * g0[0]; acc[1] += xv * g0[1]; acc[2] += xv * g0[2]; acc[3] += xv * g0[3];
    acc[4] += xv * g1[0]; acc[5] += xv * g1[1]; acc[6] += xv * g1[2]; acc[7] += xv * g1[3];
  }
  #pragma unroll
  for (int e = 0; e < EE; ++e) {
    #pragma unroll
    for (int off = 32; off > 0; off >>= 1) acc[e] += __shfl_xor(acc[e], off);
  }
  if (lane == 0) {
    float m = acc[0];
    #pragma unroll
    for (int e = 1; e < EE; ++e) m = fmaxf(m, acc[e]);
    float p[EE], s = 0.f;
    #pragma unroll
    for (int e = 0; e < EE; ++e) { p[e] = expf(acc[e] - m); s += p[e]; }
    float inv = 1.f / s;
    #pragma unroll
    for (int e = 0; e < EE; ++e) p[e] *= inv;
    int e1 = 0;
    #pragma unroll
    for (int e = 1; e < EE; ++e) if (p[e] > p[e1]) e1 = e;
    int e2 = (e1 == 0) ? 1 : 0;
    #pragma unroll
    for (int e = 0; e < EE; ++e) if (e != e1 && p[e] > p[e2]) e2 = e;
    tope[2 * t] = e1;  tope[2 * t + 1] = e2;
    topw[2 * t] = p[e1]; topw[2 * t + 1] = p[e2];
    atomicAdd(&counts[e1], 1);
    atomicAdd(&counts[e2], 1);
  }
}

// ---------------- per-expert padded row offsets ----------------
__global__ void offsets_k(const int* __restrict__ counts, int* __restrict__ rowoff) {
  if (threadIdx.x == 0) {
    int off = 0;
    #pragma unroll
    for (int e = 0; e < EE; ++e) {
      rowoff[e] = off;
      off += ((counts[e] + BM - 1) / BM) * BM;
    }
  }
}

// ---------------- scatter token ids/weights into expert-sorted slots ----------------
__global__ __launch_bounds__(256) void scatter_k(
    const int* __restrict__ tope, const float* __restrict__ topw,
    const int* __restrict__ rowoff, int* __restrict__ fill,
    int* __restrict__ ids, float* __restrict__ wts) {
  const int t = blockIdx.x * 256 + threadIdx.x;
  if (t >= T_TOK) return;
  #pragma unroll
  for (int j = 0; j < 2; ++j) {
    int e = tope[2 * t + j];
    int pos = rowoff[e] + atomicAdd(&fill[e], 1);
    ids[pos] = t;
    wts[pos] = topw[2 * t + j];
  }
}

static __device__ __forceinline__ int find_expert(
    const int* counts, const int* rowoff, int mt) {
  int expert = -1;
  #pragma unroll
  for (int e = 0; e < EE; ++e) {
    int rs = rowoff[e];
    int tl = (counts[e] + BM - 1) / BM;
    if (mt * BM >= rs && mt * BM < rs + tl * BM) expert = e;
  }
  return expert;
}

// XCD-aware bijective swizzle, mt-fastest (weight panels 512MB > L3; same-nt
// m-tiles share a 2MB B-panel -> XCD L2 reuse). nwg % 8 == 0 for both grids.
static __device__ __forceinline__ void xcd_map(int* nt, int* mt) {
  int gx = gridDim.x, gy = gridDim.y;
  int nwg = gx * gy;
  int lin = blockIdx.y * gx + blockIdx.x;
  int q = nwg >> 3;
  int s = (lin & 7) * q + (lin >> 3);
  *nt = s / gy;
  *mt = s % gy;
}

// ---------------- GEMM1: H = silu(Xb@W1) * (Xb@W3), bf16 out ----------------
// R4 structure exactly; MFMA 32x32x16 (2x2 per wave per mat), A from xb (bf16).
__global__ __launch_bounds__(256, 2) void gemm1_k(
    const unsigned short* __restrict__ xb, const float* __restrict__ w1,
    const float* __restrict__ w3, const int* __restrict__ counts,
    const int* __restrict__ rowoff, const int* __restrict__ ids,
    unsigned short* __restrict__ H) {
  int nt, mt;
  xcd_map(&nt, &mt);
  const int expert = find_expert(counts, rowoff, mt);
  if (expert < 0) return;
  const int m0 = mt * BM, n0 = nt * BN;

  __shared__ unsigned short sA[BM * BK];
  __shared__ unsigned short sB0[BN * BK];
  __shared__ unsigned short sB1[BN * BK];

  const int tid = threadIdx.x;
  const int lane = tid & 63;
  const int wid = tid >> 6;
  const int wm = (wid >> 1) * 64, wn = (wid & 1) * 64;
  const int l32 = lane & 31;     // row/col within 32x32 tile
  const int khi = lane >> 5;     // k-half selector (0/1)

  // A staging (bf16): thread covers rows (tid>>3)+32i, chunk tid&7 (16B = 8 k)
  const int a_row0 = tid >> 3;
  const int a_ch = tid & 7;
  const unsigned short* aptr[4];
  #pragma unroll
  for (int g = 0; g < 4; ++g)
    aptr[g] = xb + (size_t)ids[m0 + a_row0 + g * 32] * DD + a_ch * 8;

  // B staging: thread covers 4 f-rows x 8 k per mat, transposed+cvt into LDS
  const int b_f4 = (tid & 31) * 4;
  const int b_k8 = (tid >> 5) * 8;
  const float* wb1 = w1 + (size_t)expert * DD * FF + n0 + b_f4 + (size_t)b_k8 * FF;
  const float* wb3 = w3 + (size_t)expert * DD * FF + n0 + b_f4 + (size_t)b_k8 * FF;

  v16f acc1[2][2], acc3[2][2];
  #pragma unroll
  for (int i = 0; i < 2; ++i)
    #pragma unroll
    for (int j = 0; j < 2; ++j) {
      acc1[i][j] = (v16f)(0.f);
      acc3[i][j] = (v16f)(0.f);
    }

  for (int kt = 0; kt < DD / BK; ++kt) {
    #pragma unroll
    for (int g = 0; g < 4; ++g) {
      v8s h = *(const v8s*)(aptr[g] + (size_t)kt * BK);
      *(v8s*)((char*)sA + SWZ(a_row0 + g * 32, a_ch * 16)) = h;
    }
    {
      const float* p = wb1 + (size_t)kt * BK * FF;
      v4f r[8];
      #pragma unroll
      for (int j = 0; j < 8; ++j) r[j] = *(const v4f*)(p + (size_t)j * FF);
      #pragma unroll
      for (int c = 0; c < 4; ++c) {
        v8s h;
        #pragma unroll
        for (int j = 0; j < 8; ++j) h[j] = f2bf(r[j][c]);
        *(v8s*)((char*)sB0 + SWZ(b_f4 + c, b_k8 * 2)) = h;
      }
      p = wb3 + (size_t)kt * BK * FF;
      #pragma unroll
      for (int j = 0; j < 8; ++j) r[j] = *(const v4f*)(p + (size_t)j * FF);
      #pragma unroll
      for (int c = 0; c < 4; ++c) {
        v8s h;
        #pragma unroll
        for (int j = 0; j < 8; ++j) h[j] = f2bf(r[j][c]);
        *(v8s*)((char*)sB1 + SWZ(b_f4 + c, b_k8 * 2)) = h;
      }
    }
    __syncthreads();
    // 4 K-slices of 16; frag = 8 consecutive k per lane: k0 = ks*16 + khi*8
    #pragma unroll
    for (int ks = 0; ks < 4; ++ks) {
      const int kb = (ks * 2 + khi) * 16;    // byte chunk col
      v8s a[2], b1[2], b3[2];
      #pragma unroll
      for (int m = 0; m < 2; ++m)
        a[m] = *(const v8s*)((const char*)sA + SWZ(wm + m * 32 + l32, kb));
      #pragma unroll
      for (int n = 0; n < 2; ++n) {
        b1[n] = *(const v8s*)((const char*)sB0 + SWZ(wn + n * 32 + l32, kb));
        b3[n] = *(const v8s*)((const char*)sB1 + SWZ(wn + n * 32 + l32, kb));
      }
      #pragma unroll
      for (int m = 0; m < 2; ++m)
        #pragma unroll
        for (int n = 0; n < 2; ++n) {
          acc1[m][n] = __builtin_amdgcn_mfma_f32_32x32x16_bf16(a[m], b1[n], acc1[m][n], 0, 0, 0);
          acc3[m][n] = __builtin_amdgcn_mfma_f32_32x32x16_bf16(a[m], b3[n], acc3[m][n], 0, 0, 0);
        }
    }
    __syncthreads();
  }
  // C/D layout (32x32): col = lane&31, row = (r&3) + 8*(r>>2) + 4*(lane>>5)
  #pragma unroll
  for (int m = 0; m < 2; ++m)
    #pragma unroll
    for (int n = 0; n < 2; ++n)
      #pragma unroll
      for (int r = 0; r < 16; ++r) {
        int row = wm + m * 32 + (r & 3) + 8 * (r >> 2) + 4 * khi;
        int col = wn + n * 32 + l32;
        float g = acc1[m][n][r];
        float u = acc3[m][n][r];
        float hv = (g / (1.f + expf(-g))) * u;
        H[(size_t)(m0 + row) * FF + (n0 + col)] = (unsigned short)f2bf(hv);
      }
}

// ---------------- GEMM2: out[tok] += w * (H @ W2) ----------------
__global__ __launch_bounds__(256, 2) void gemm2_k(
    const unsigned short* __restrict__ H, const float* __restrict__ w2,
    const int* __restrict__ counts, const int* __restrict__ rowoff,
    const int* __restrict__ ids, const float* __restrict__ wts,
    float* __restrict__ out) {
  int nt, mt;
  xcd_map(&nt, &mt);
  const int expert = find_expert(counts, rowoff, mt);
  if (expert < 0) return;
  const int m0 = mt * BM, n0 = nt * BN;

  __shared__ unsigned short sA[BM * BK];
  __shared__ unsigned short sB[BN * BK];

  const int tid = threadIdx.x;
  const int lane = tid & 63;
  const int wid = tid >> 6;
  const int wm = (wid >> 1) * 64, wn = (wid & 1) * 64;
  const int l32 = lane & 31;
  const int khi = lane >> 5;

  const int a_row0 = tid >> 3;
  const int a_ch = tid & 7;
  const unsigned short* ha = H + (size_t)(m0 + a_row0) * FF + a_ch * 8;
  const int b_f4 = (tid & 31) * 4;   // output cols (d)
  const int b_k8 = (tid >> 5) * 8;   // k rows (f)
  const float* wb = w2 + (size_t)expert * FF * DD + n0 + b_f4 + (size_t)b_k8 * DD;

  v16f acc[2][2];
  #pragma unroll
  for (int i = 0; i < 2; ++i)
    #pragma unroll
    for (int j = 0; j < 2; ++j) acc[i][j] = (v16f)(0.f);

  for (int kt = 0; kt < FF / BK; ++kt) {
    #pragma unroll
    for (int g = 0; g < 4; ++g) {
      v8s h = *(const v8s*)(ha + (size_t)g * 32 * FF + kt * BK);
      *(v8s*)((char*)sA + SWZ(a_row0 + g * 32, a_ch * 16)) = h;
    }
    {
      const float* p = wb + (size_t)kt * BK * DD;
      v4f r[8];
      #pragma unroll
      for (int j = 0; j < 8; ++j) r[j] = *(const v4f*)(p + (size_t)j * DD);
      #pragma unroll
      for (int c = 0; c < 4; ++c) {
        v8s h;
        #pragma unroll
        for (int j = 0; j < 8; ++j) h[j] = f2bf(r[j][c]);
        *(v8s*)((char*)sB + SWZ(b_f4 + c, b_k8 * 2)) = h;
      }
    }
    __syncthreads();
    #pragma unroll
    for (int ks = 0; ks < 4; ++ks) {
      const int kb = (ks * 2 + khi) * 16;
      v8s a[2], b[2];
      #pragma unroll
      for (int m = 0; m < 2; ++m)
        a[m] = *(const v8s*)((const char*)sA + SWZ(wm + m * 32 + l32, kb));
      #pragma unroll
      for (int n = 0; n < 2; ++n)
        b[n] = *(const v8s*)((const char*)sB + SWZ(wn + n * 32 + l32, kb));
      #pragma unroll
      for (int m = 0; m < 2; ++m)
        #pragma unroll
        for (int n = 0; n < 2; ++n)
          acc[m][n] = __builtin_amdgcn_mfma_f32_32x32x16_bf16(a[m], b[n], acc[m][n], 0, 0, 0);
    }
    __syncthreads();
  }
  #pragma unroll
  for (int m = 0; m < 2; ++m)
    #pragma unroll
    for (int r = 0; r < 16; ++r) {
      int row = m0 + wm + m * 32 + (r & 3) + 8 * (r >> 2) + 4 * khi;
      float wgt = wts[row];
      if (wgt != 0.f) {   // skip zero-weight padding rows
        float* orow = out + (size_t)ids[row] * DD + n0 + wn + l32;
        #pragma unroll
        for (int n = 0; n < 2; ++n)
          atomicAdd(orow + n * 32, wgt * acc[m][n][r]);
      }
    }
}

extern "C" void kernel_launch(void* const* d_in, const int* in_sizes, int n_in,
                              void* d_out, int out_size, void* d_ws, size_t ws_size,
                              hipStream_t stream) {
  const float* x  = (const float*)d_in[0];
  const float* gw = (const float*)d_in[1];
  const float* w1 = (const float*)d_in[2];
  const float* w3 = (const float*)d_in[3];
  const float* w2 = (const float*)d_in[4];
  float* out = (float*)d_out;
  char* ws = (char*)d_ws;

  int*   counts = (int*)(ws + WS_COUNTS);
  int*   fill   = (int*)(ws + WS_FILL);
  int*   rowoff = (int*)(ws + WS_ROWOFF);
  int*   tope   = (int*)(ws + WS_TOPE);
  float* topw   = (float*)(ws + WS_TOPW);
  int*   ids    = (int*)(ws + WS_IDS);
  float* wts    = (float*)(ws + WS_WTS);
  unsigned short* xb = (unsigned short*)(ws + WS_XB);
  unsigned short* H  = (unsigned short*)(ws + WS_H);

  hipMemsetAsync(ws, 0, WS_ZERO, stream);
  hipMemsetAsync(d_out, 0, (size_t)out_size * sizeof(float), stream);

  xbf_k<<<T_TOK * DD / (256 * 8), 256, 0, stream>>>(x, xb);
  router_k<<<T_TOK / 4, 256, 0, stream>>>(x, gw, counts, tope, topw);
  offsets_k<<<1, 64, 0, stream>>>(counts, rowoff);
  scatter_k<<<T_TOK / 256, 256, 0, stream>>>(tope, topw, rowoff, fill, ids, wts);
  gemm1_k<<<dim3(FF / BN, MT_MAX), 256, 0, stream>>>(xb, w1, w3, counts, rowoff, ids, H);
  gemm2_k<<<dim3(DD / BN, MT_MAX), 256, 0, stream>>>(H, w2, counts, rowoff, ids, wts, out);
}

// Round 9
// 514.229 us; speedup vs baseline: 1.9589x; 1.0598x over previous
//
#include <hip/hip_runtime.h>

typedef short v8s __attribute__((ext_vector_type(8)));
typedef float v4f __attribute__((ext_vector_type(4)));
typedef float v16f __attribute__((ext_vector_type(16)));

#define T_TOK 2048
#define DD 2048
#define FF 4096
#define EE 8
#define BM 128
#define BN 128
#define BK 64
#define MT_MAX 40
#define MAXROWS 5120

// workspace layout (bytes)
#define WS_COUNTS 0
#define WS_FILL   32
#define WS_ROWOFF 64
#define WS_TOPE   128
#define WS_TOPW   (WS_TOPE + T_TOK * 2 * 4)   // 16512
#define WS_IDS    (WS_TOPW + T_TOK * 2 * 4)   // 32896
#define WS_WTS    (WS_IDS + MAXROWS * 4)      // 53376
#define WS_ZERO   (WS_WTS + MAXROWS * 4)      // 73856 zeroed each launch
#define WS_XB     73984ul                     // bf16 X [2048][2048] = 8 MB
#define WS_H      (WS_XB + 8388608ul)         // bf16 H [5120][4096] = 41.9 MB

// chunk swizzle within a [row][64 bf16] LDS tile (128B rows, 8x16B chunks)
#define SW(r)     ((((r) ^ ((r) >> 3)) & 7))
#define SWZ(r, kb) ((r) * 128 + ((kb) ^ (SW(r) << 4)))

#define VMCNTN(N) asm volatile("s_waitcnt vmcnt(" #N ")" ::: "memory")
#define VMCNT0()  asm volatile("s_waitcnt vmcnt(0)" ::: "memory")
#define LGKM0()   asm volatile("s_waitcnt lgkmcnt(0)" ::: "memory")
#define BARR()    __builtin_amdgcn_s_barrier()
#define SCHEDB()  __builtin_amdgcn_sched_barrier(0)

static __device__ __forceinline__ short f2bf(float f) {
  return __builtin_bit_cast(short, static_cast<__bf16>(f));
}

// async global->LDS 16B/lane; LDS dest = wave-uniform base + lane*16 (HW).
static __device__ __forceinline__ void gload_lds16(const void* g, void* l) {
  __builtin_amdgcn_global_load_lds(
      (const __attribute__((address_space(1))) unsigned int*)g,
      (__attribute__((address_space(3))) unsigned int*)l, 16, 0, 0);
}

// ---------------- X -> bf16 ----------------
__global__ __launch_bounds__(256) void xbf_k(const float* __restrict__ x,
                                             unsigned short* __restrict__ xb) {
  const int i = (blockIdx.x * 256 + threadIdx.x) * 8;
  v4f a = *(const v4f*)(x + i);
  v4f b = *(const v4f*)(x + i + 4);
  v8s h;
  h[0] = f2bf(a[0]); h[1] = f2bf(a[1]); h[2] = f2bf(a[2]); h[3] = f2bf(a[3]);
  h[4] = f2bf(b[0]); h[5] = f2bf(b[1]); h[6] = f2bf(b[2]); h[7] = f2bf(b[3]);
  *(v8s*)(xb + i) = h;
}

// ---------------- router: fp32 logits, softmax, top-2 ----------------
__global__ __launch_bounds__(256) void router_k(
    const float* __restrict__ x, const float* __restrict__ gw,
    int* __restrict__ counts, int* __restrict__ tope, float* __restrict__ topw) {
  const int lane = threadIdx.x & 63;
  const int t = blockIdx.x * 4 + (threadIdx.x >> 6);
  if (t >= T_TOK) return;
  float acc[EE] = {0.f, 0.f, 0.f, 0.f, 0.f, 0.f, 0.f, 0.f};
  const float* xr = x + (size_t)t * DD;
  for (int i = 0; i < DD / 64; ++i) {
    int k = i * 64 + lane;
    float xv = xr[k];
    const v4f* g = (const v4f*)(gw + (size_t)k * EE);
    v4f g0 = g[0], g1 = g[1];
    acc[0] += xv * g0[0]; acc[1] += xv * g0[1]; acc[2] += xv * g0[2]; acc[3] += xv * g0[3];
    acc[4] += xv * g1[0]; acc[5] += xv * g1[1]; acc[6] += xv * g1[2]; acc[7] += xv * g1[3];
  }
  #pragma unroll
  for (int e = 0; e < EE; ++e) {
    #pragma unroll
    for (int off = 32; off > 0; off >>= 1) acc[e] += __shfl_xor(acc[e], off);
  }
  if (lane == 0) {
    float m = acc[0];
    #pragma unroll
    for (int e = 1; e < EE; ++e) m = fmaxf(m, acc[e]);
    float p[EE], s = 0.f;
    #pragma unroll
    for (int e = 0; e < EE; ++e) { p[e] = expf(acc[e] - m); s += p[e]; }
    float inv = 1.f / s;
    #pragma unroll
    for (int e = 0; e < EE; ++e) p[e] *= inv;
    int e1 = 0;
    #pragma unroll
    for (int e = 1; e < EE; ++e) if (p[e] > p[e1]) e1 = e;
    int e2 = (e1 == 0) ? 1 : 0;
    #pragma unroll
    for (int e = 0; e < EE; ++e) if (e != e1 && p[e] > p[e2]) e2 = e;
    tope[2 * t] = e1;  tope[2 * t + 1] = e2;
    topw[2 * t] = p[e1]; topw[2 * t + 1] = p[e2];
    atomicAdd(&counts[e1], 1);
    atomicAdd(&counts[e2], 1);
  }
}

// ---------------- per-expert padded row offsets ----------------
__global__ void offsets_k(const int* __restrict__ counts, int* __restrict__ rowoff) {
  if (threadIdx.x == 0) {
    int off = 0;
    #pragma unroll
    for (int e = 0; e < EE; ++e) {
      rowoff[e] = off;
      off += ((counts[e] + BM - 1) / BM) * BM;
    }
  }
}

// ---------------- scatter ----------------
__global__ __launch_bounds__(256) void scatter_k(
    const int* __restrict__ tope, const float* __restrict__ topw,
    const int* __restrict__ rowoff, int* __restrict__ fill,
    int* __restrict__ ids, float* __restrict__ wts) {
  const int t = blockIdx.x * 256 + threadIdx.x;
  if (t >= T_TOK) return;
  #pragma unroll
  for (int j = 0; j < 2; ++j) {
    int e = tope[2 * t + j];
    int pos = rowoff[e] + atomicAdd(&fill[e], 1);
    ids[pos] = t;
    wts[pos] = topw[2 * t + j];
  }
}

static __device__ __forceinline__ int find_expert(
    const int* counts, const int* rowoff, int mt) {
  int expert = -1;
  #pragma unroll
  for (int e = 0; e < EE; ++e) {
    int rs = rowoff[e];
    int tl = (counts[e] + BM - 1) / BM;
    if (mt * BM >= rs && mt * BM < rs + tl * BM) expert = e;
  }
  return expert;
}

// XCD-aware bijective swizzle, mt-fastest. nwg % 8 == 0 for both grids.
static __device__ __forceinline__ void xcd_map(int* nt, int* mt) {
  int gx = gridDim.x, gy = gridDim.y;
  int nwg = gx * gy;
  int lin = blockIdx.y * gx + blockIdx.x;
  int q = nwg >> 3;
  int s = (lin & 7) * q + (lin >> 3);
  *nt = s / gy;
  *mt = s % gy;
}

// ---------------- GEMM1: H = silu(Xb@W1) * (Xb@W3), bf16 out ----------------
// R8 structure; staging reordered: A via gload_lds (src-preswizzled), B
// prefetched to VGPR one kt ahead (issued pre-compute, consumed post-barrier).
__global__ __launch_bounds__(256, 2) void gemm1_k(
    const unsigned short* __restrict__ xb, const float* __restrict__ w1,
    const float* __restrict__ w3, const int* __restrict__ counts,
    const int* __restrict__ rowoff, const int* __restrict__ ids,
    unsigned short* __restrict__ H) {
  int nt, mt;
  xcd_map(&nt, &mt);
  const int expert = find_expert(counts, rowoff, mt);
  if (expert < 0) return;
  const int m0 = mt * BM, n0 = nt * BN;

  __shared__ unsigned short sA[BM * BK];
  __shared__ unsigned short sB0[BN * BK];
  __shared__ unsigned short sB1[BN * BK];

  const int tid = threadIdx.x;
  const int lane = tid & 63;
  const int wid = tid >> 6;
  const int wm = (wid >> 1) * 64, wn = (wid & 1) * 64;
  const int l32 = lane & 31;
  const int khi = lane >> 5;

  // A gload sources: 4 instr/wave, rows wid*32+i*8+(lane>>3), chunk pre-swizzled
  const unsigned short* ga[4];
  #pragma unroll
  for (int i = 0; i < 4; ++i) {
    int r = wid * 32 + i * 8 + (lane >> 3);
    ga[i] = xb + (size_t)ids[m0 + r] * DD + (((lane & 7) ^ SW(r)) << 3);
  }

  // B staging: thread covers 4 f-rows x 8 k per mat
  const int b_f4 = (tid & 31) * 4;
  const int b_k8 = (tid >> 5) * 8;
  const float* wb1 = w1 + (size_t)expert * DD * FF + n0 + b_f4 + (size_t)b_k8 * FF;
  const float* wb3 = w3 + (size_t)expert * DD * FF + n0 + b_f4 + (size_t)b_k8 * FF;

  v4f r1[8], r3[8];
  #define G1_ALDS(KT) { _Pragma("unroll") for (int i_ = 0; i_ < 4; ++i_)        \
      gload_lds16(ga[i_] + (size_t)(KT) * BK,                                   \
                  (char*)sA + (wid * 32 + i_ * 8) * 128); }
  #define G1_BL(KT) {                                                           \
      const float* p_ = wb1 + (size_t)(KT) * BK * FF;                           \
      _Pragma("unroll") for (int j_ = 0; j_ < 8; ++j_)                          \
        r1[j_] = *(const v4f*)(p_ + (size_t)j_ * FF);                           \
      p_ = wb3 + (size_t)(KT) * BK * FF;                                        \
      _Pragma("unroll") for (int j_ = 0; j_ < 8; ++j_)                          \
        r3[j_] = *(const v4f*)(p_ + (size_t)j_ * FF); }
  #define G1_BW() { _Pragma("unroll") for (int c_ = 0; c_ < 4; ++c_) {          \
      v8s h1_, h3_;                                                             \
      _Pragma("unroll") for (int j_ = 0; j_ < 8; ++j_) {                        \
        h1_[j_] = f2bf(r1[j_][c_]); h3_[j_] = f2bf(r3[j_][c_]); }               \
      *(v8s*)((char*)sB0 + SWZ(b_f4 + c_, b_k8 * 2)) = h1_;                     \
      *(v8s*)((char*)sB1 + SWZ(b_f4 + c_, b_k8 * 2)) = h3_; } }

  v16f acc1[2][2], acc3[2][2];
  #pragma unroll
  for (int i = 0; i < 2; ++i)
    #pragma unroll
    for (int j = 0; j < 2; ++j) {
      acc1[i][j] = (v16f)(0.f);
      acc3[i][j] = (v16f)(0.f);
    }

  G1_BL(0);                        // B(0) prefetch

  for (int kt = 0; kt < DD / BK; ++kt) {
    G1_ALDS(kt);                   // A(kt) -> sA async, zero VGPR
    SCHEDB();
    G1_BW();                       // consume B(kt) regs (cvt+write)
    if (kt + 1 < DD / BK) {
      G1_BL(kt + 1);               // issue B(kt+1); flies across compute
      SCHEDB();
      VMCNTN(16);                  // wait the 4 A-gloads only
    } else {
      VMCNT0();
    }
    LGKM0(); BARR();
    SCHEDB();
    #pragma unroll
    for (int ks = 0; ks < 4; ++ks) {
      const int kb = (ks * 2 + khi) * 16;
      v8s a[2], b1[2], b3[2];
      #pragma unroll
      for (int m = 0; m < 2; ++m)
        a[m] = *(const v8s*)((const char*)sA + SWZ(wm + m * 32 + l32, kb));
      #pragma unroll
      for (int n = 0; n < 2; ++n) {
        b1[n] = *(const v8s*)((const char*)sB0 + SWZ(wn + n * 32 + l32, kb));
        b3[n] = *(const v8s*)((const char*)sB1 + SWZ(wn + n * 32 + l32, kb));
      }
      #pragma unroll
      for (int m = 0; m < 2; ++m)
        #pragma unroll
        for (int n = 0; n < 2; ++n) {
          acc1[m][n] = __builtin_amdgcn_mfma_f32_32x32x16_bf16(a[m], b1[n], acc1[m][n], 0, 0, 0);
          acc3[m][n] = __builtin_amdgcn_mfma_f32_32x32x16_bf16(a[m], b3[n], acc3[m][n], 0, 0, 0);
        }
    }
    BARR();                        // all waves done reading sA/sB
  }
  // C/D layout (32x32): col = lane&31, row = (r&3) + 8*(r>>2) + 4*(lane>>5)
  #pragma unroll
  for (int m = 0; m < 2; ++m)
    #pragma unroll
    for (int n = 0; n < 2; ++n)
      #pragma unroll
      for (int r = 0; r < 16; ++r) {
        int row = wm + m * 32 + (r & 3) + 8 * (r >> 2) + 4 * khi;
        int col = wn + n * 32 + l32;
        float g = acc1[m][n][r];
        float u = acc3[m][n][r];
        float hv = (g / (1.f + expf(-g))) * u;
        H[(size_t)(m0 + row) * FF + (n0 + col)] = (unsigned short)f2bf(hv);
      }
}

// ---------------- GEMM2: out[tok] += w * (H @ W2) ----------------
__global__ __launch_bounds__(256, 2) void gemm2_k(
    const unsigned short* __restrict__ H, const float* __restrict__ w2,
    const int* __restrict__ counts, const int* __restrict__ rowoff,
    const int* __restrict__ ids, const float* __restrict__ wts,
    float* __restrict__ out) {
  int nt, mt;
  xcd_map(&nt, &mt);
  const int expert = find_expert(counts, rowoff, mt);
  if (expert < 0) return;
  const int m0 = mt * BM, n0 = nt * BN;

  __shared__ unsigned short sA[BM * BK];
  __shared__ unsigned short sB[BN * BK];

  const int tid = threadIdx.x;
  const int lane = tid & 63;
  const int wid = tid >> 6;
  const int wm = (wid >> 1) * 64, wn = (wid & 1) * 64;
  const int l32 = lane & 31;
  const int khi = lane >> 5;

  const unsigned short* ga[4];
  #pragma unroll
  for (int i = 0; i < 4; ++i) {
    int r = wid * 32 + i * 8 + (lane >> 3);
    ga[i] = H + (size_t)(m0 + r) * FF + (((lane & 7) ^ SW(r)) << 3);
  }

  const int b_f4 = (tid & 31) * 4;   // output cols (d)
  const int b_k8 = (tid >> 5) * 8;   // k rows (f)
  const float* wb = w2 + (size_t)expert * FF * DD + n0 + b_f4 + (size_t)b_k8 * DD;

  v4f rb[8];
  #define G2_ALDS(KT) { _Pragma("unroll") for (int i_ = 0; i_ < 4; ++i_)        \
      gload_lds16(ga[i_] + (size_t)(KT) * BK,                                   \
                  (char*)sA + (wid * 32 + i_ * 8) * 128); }
  #define G2_BL(KT) { const float* p_ = wb + (size_t)(KT) * BK * DD;            \
      _Pragma("unroll") for (int j_ = 0; j_ < 8; ++j_)                          \
        rb[j_] = *(const v4f*)(p_ + (size_t)j_ * DD); }
  #define G2_BW() { _Pragma("unroll") for (int c_ = 0; c_ < 4; ++c_) {          \
      v8s h_;                                                                   \
      _Pragma("unroll") for (int j_ = 0; j_ < 8; ++j_) h_[j_] = f2bf(rb[j_][c_]);\
      *(v8s*)((char*)sB + SWZ(b_f4 + c_, b_k8 * 2)) = h_; } }

  v16f acc[2][2];
  #pragma unroll
  for (int i = 0; i < 2; ++i)
    #pragma unroll
    for (int j = 0; j < 2; ++j) acc[i][j] = (v16f)(0.f);

  G2_BL(0);

  for (int kt = 0; kt < FF / BK; ++kt) {
    G2_ALDS(kt);
    SCHEDB();
    G2_BW();
    if (kt + 1 < FF / BK) {
      G2_BL(kt + 1);
      SCHEDB();
      VMCNTN(8);                   // wait the 4 A-gloads only
    } else {
      VMCNT0();
    }
    LGKM0(); BARR();
    SCHEDB();
    #pragma unroll
    for (int ks = 0; ks < 4; ++ks) {
      const int kb = (ks * 2 + khi) * 16;
      v8s a[2], b[2];
      #pragma unroll
      for (int m = 0; m < 2; ++m)
        a[m] = *(const v8s*)((const char*)sA + SWZ(wm + m * 32 + l32, kb));
      #pragma unroll
      for (int n = 0; n < 2; ++n)
        b[n] = *(const v8s*)((const char*)sB + SWZ(wn + n * 32 + l32, kb));
      #pragma unroll
      for (int m = 0; m < 2; ++m)
        #pragma unroll
        for (int n = 0; n < 2; ++n)
          acc[m][n] = __builtin_amdgcn_mfma_f32_32x32x16_bf16(a[m], b[n], acc[m][n], 0, 0, 0);
    }
    BARR();
  }
  #pragma unroll
  for (int m = 0; m < 2; ++m)
    #pragma unroll
    for (int r = 0; r < 16; ++r) {
      int row = m0 + wm + m * 32 + (r & 3) + 8 * (r >> 2) + 4 * khi;
      float wgt = wts[row];
      if (wgt != 0.f) {
        float* orow = out + (size_t)ids[row] * DD + n0 + wn + l32;
        #pragma unroll
        for (int n = 0; n < 2; ++n)
          atomicAdd(orow + n * 32, wgt * acc[m][n][r]);
      }
    }
}

extern "C" void kernel_launch(void* const* d_in, const int* in_sizes, int n_in,
                              void* d_out, int out_size, void* d_ws, size_t ws_size,
                              hipStream_t stream) {
  const float* x  = (const float*)d_in[0];
  const float* gw = (const float*)d_in[1];
  const float* w1 = (const float*)d_in[2];
  const float* w3 = (const float*)d_in[3];
  const float* w2 = (const float*)d_in[4];
  float* out = (float*)d_out;
  char* ws = (char*)d_ws;

  int*   counts = (int*)(ws + WS_COUNTS);
  int*   fill   = (int*)(ws + WS_FILL);
  int*   rowoff = (int*)(ws + WS_ROWOFF);
  int*   tope   = (int*)(ws + WS_TOPE);
  float* topw   = (float*)(ws + WS_TOPW);
  int*   ids    = (int*)(ws + WS_IDS);
  float* wts    = (float*)(ws + WS_WTS);
  unsigned short* xb = (unsigned short*)(ws + WS_XB);
  unsigned short* H  = (unsigned short*)(ws + WS_H);

  hipMemsetAsync(ws, 0, WS_ZERO, stream);
  hipMemsetAsync(d_out, 0, (size_t)out_size * sizeof(float), stream);

  xbf_k<<<T_TOK * DD / (256 * 8), 256, 0, stream>>>(x, xb);
  router_k<<<T_TOK / 4, 256, 0, stream>>>(x, gw, counts, tope, topw);
  offsets_k<<<1, 64, 0, stream>>>(counts, rowoff);
  scatter_k<<<T_TOK / 256, 256, 0, stream>>>(tope, topw, rowoff, fill, ids, wts);
  gemm1_k<<<dim3(FF / BN, MT_MAX), 256, 0, stream>>>(xb, w1, w3, counts, rowoff, ids, H);
  gemm2_k<<<dim3(DD / BN, MT_MAX), 256, 0, stream>>>(H, w2, counts, rowoff, ids, wts, out);
}